// Round 4
// baseline (194.884 us; speedup 1.0000x reference)
//
#include <hip/hip_runtime.h>
#include <hip/hip_bf16.h>

// Problem constants
#define NN     3072
#define NW32   96          // 3072/32 u32-words per maskT row
#define INCH   128
#define HID    256
#define NHEADS 12
#define PLANE  9437184LL   // 3072*3072

typedef __attribute__((ext_vector_type(8))) short     s16x8;
typedef __attribute__((ext_vector_type(4))) float     f32x4;
typedef __attribute__((ext_vector_type(8))) unsigned short u16x8;
typedef __attribute__((ext_vector_type(4))) unsigned int   u32x4;

__device__ inline unsigned short bf16_rne(float f) {
    unsigned int u = __float_as_uint(f);
    u += 0x7FFFu + ((u >> 16) & 1u);
    return (unsigned short)(u >> 16);
}

// ---------------------------------------------------------------------------
// L1: role-split launch.
//  blocks [0,1152): adj — stream attn (453 MB). Tile 256t x 32s. c-outer loop:
//      8 independent row-accumulators, uniform plane base + invariant voffsets
//      (no per-load addr math), nontemporal f32x4 loads.
//  blocks [1152,1536): y1 — y1t[d][s] = bf16((x@W1)[s][d]) transposed store.
// ---------------------------------------------------------------------------
__global__ __launch_bounds__(256) void k_adj_y1(const float* __restrict__ attn,
                                                const float* __restrict__ agg_w,
                                                const float* __restrict__ agg_b,
                                                const float* __restrict__ x,
                                                const float* __restrict__ W1,
                                                unsigned int* __restrict__ maskT32,
                                                unsigned short* __restrict__ y1t) {
    __shared__ unsigned int chunkU[4][64];   // adj transpose staging
    __shared__ float xs[8][INCH];            // y1

    if (blockIdx.x < 1152) {
        const int w = threadIdx.x >> 6, l = threadIdx.x & 63;
        const int t0 = (blockIdx.x % 12) * 256;
        const int s0 = (blockIdx.x / 12) * 32;
        const int tb = t0 + 4 * l;
        const int srow = s0 + 8 * w;
        const float thr = -agg_b[0];

        f32x4 acc[8];
#pragma unroll
        for (int i = 0; i < 8; ++i) acc[i] = (f32x4){0.f, 0.f, 0.f, 0.f};

        const int voff = srow * NN + tb;   // 32-bit, loop-invariant
#pragma unroll 1
        for (int c = 0; c < NHEADS; ++c) {
            const float* pc = attn + (long long)c * PLANE;   // uniform base
            const float wcv = agg_w[c];
#pragma unroll
            for (int i = 0; i < 8; ++i) {
                f32x4 v = __builtin_nontemporal_load((const f32x4*)(pc + voff + i * NN));
                acc[i][0] = fmaf(wcv, v[0], acc[i][0]);
                acc[i][1] = fmaf(wcv, v[1], acc[i][1]);
                acc[i][2] = fmaf(wcv, v[2], acc[i][2]);
                acc[i][3] = fmaf(wcv, v[3], acc[i][3]);
            }
        }

        unsigned int colb = 0;
#pragma unroll
        for (int i = 0; i < 8; ++i) {
            const int s = srow + i;
            colb |= ((acc[i][0] > thr || s == tb + 0) ? 1u : 0u) << (0 + i);
            colb |= ((acc[i][1] > thr || s == tb + 1) ? 1u : 0u) << (8 + i);
            colb |= ((acc[i][2] > thr || s == tb + 2) ? 1u : 0u) << (16 + i);
            colb |= ((acc[i][3] > thr || s == tb + 3) ? 1u : 0u) << (24 + i);
        }
        chunkU[w][l] = colb;
        __syncthreads();
        const int l2 = threadIdx.x >> 2, j = threadIdx.x & 3;
        unsigned int word =  ((chunkU[0][l2] >> (8 * j)) & 0xFFu)
                          | (((chunkU[1][l2] >> (8 * j)) & 0xFFu) << 8)
                          | (((chunkU[2][l2] >> (8 * j)) & 0xFFu) << 16)
                          | (((chunkU[3][l2] >> (8 * j)) & 0xFFu) << 24);
        maskT32[(long long)(t0 + threadIdx.x) * NW32 + (s0 >> 5)] = word;
    } else {
        // --- y1: block = 8 s-rows, thread = d ---
        int s0 = (blockIdx.x - 1152) * 8;
        for (int i = threadIdx.x; i < 8 * INCH; i += 256)
            xs[i >> 7][i & 127] = x[s0 * INCH + i];
        __syncthreads();
        int d = threadIdx.x;
        float acc[8] = {0, 0, 0, 0, 0, 0, 0, 0};
        for (int k = 0; k < INCH; ++k) {
            float w = W1[k * HID + d];
#pragma unroll
            for (int r = 0; r < 8; ++r) acc[r] = fmaf(xs[r][k], w, acc[r]);
        }
        u16x8 v;
#pragma unroll
        for (int r = 0; r < 8; ++r) v[r] = bf16_rne(acc[r]);
        *(u16x8*)(y1t + (long long)d * NN + s0) = v;
    }
}

// ---------------------------------------------------------------------------
// L2: deg[t] = popcount(maskT row t); dinv = rsqrt(deg); dinvb = bf16(dinv).
// Also resets the vredhead completion counter. grid 12 x 256.
// ---------------------------------------------------------------------------
__global__ __launch_bounds__(256) void k_dinv(const unsigned int* __restrict__ maskT32,
                                              float* __restrict__ dinv,
                                              unsigned short* __restrict__ dinvb,
                                              unsigned int* __restrict__ cnt) {
    if (blockIdx.x == 0 && threadIdx.x == 0) *cnt = 0u;
    int t = blockIdx.x * 256 + threadIdx.x;
    const u32x4* row = (const u32x4*)(maskT32 + (long long)t * NW32);
    int deg = 0;
#pragma unroll
    for (int i = 0; i < 24; ++i) {
        u32x4 v = row[i];
        deg += __popc(v[0]) + __popc(v[1]) + __popc(v[2]) + __popc(v[3]);
    }
    float di = rsqrtf((float)deg);   // deg >= 1 (self loop)
    dinv[t] = di;
    dinvb[t] = bf16_rne(di);
}

// ---------------------------------------------------------------------------
// L3: role-split launch.
//  blocks [0,384):   prop1 MFMA GEMM, in-register A expansion from maskT bits.
//  blocks [384,960): w2p column pass.
// ---------------------------------------------------------------------------
__global__ __launch_bounds__(256) void k_prop(const unsigned int* __restrict__ maskT32,
                                              const unsigned short* __restrict__ dinvb,
                                              const unsigned short* __restrict__ y1t,
                                              const float* __restrict__ dinv,
                                              float* __restrict__ partials,
                                              float* __restrict__ w2p) {
    if (blockIdx.x < 384) {
        const int w = threadIdx.x >> 6, l = threadIdx.x & 63;
        const int lr = l & 15, lg = l >> 4;
        const int t0 = (blockIdx.x % 48) * 64 + w * 16;
        const int d0 = ((blockIdx.x / 48) % 2) * 128;
        const int z  = blockIdx.x / 96;

        const unsigned long long* mrow =
            (const unsigned long long*)(maskT32 + (long long)(t0 + lr) * NW32) + z * 12;

        const unsigned short* B[8];
#pragma unroll
        for (int n = 0; n < 8; ++n)
            B[n] = y1t + (long long)(d0 + n * 16 + lr) * NN;

        f32x4 acc[8];
#pragma unroll
        for (int n = 0; n < 8; ++n) acc[n] = (f32x4){0.f, 0.f, 0.f, 0.f};

#pragma unroll 2
        for (int kw = 0; kw < 12; ++kw) {
            unsigned long long word = mrow[kw];
#pragma unroll
            for (int half = 0; half < 2; ++half) {
                const int k0 = z * 768 + kw * 64 + half * 32 + lg * 8;
                unsigned int bits = (unsigned int)((word >> (half * 32 + lg * 8)) & 0xFFULL);
                u16x8 dv = *(const u16x8*)(dinvb + k0);
                s16x8 av;
#pragma unroll
                for (int j = 0; j < 8; ++j)
                    av[j] = ((bits >> j) & 1u) ? (short)dv[j] : (short)0;
#pragma unroll
                for (int n = 0; n < 8; ++n) {
                    s16x8 bv = *(const s16x8*)(const void*)(B[n] + k0);
                    acc[n] = __builtin_amdgcn_mfma_f32_16x16x32_bf16(av, bv, acc[n], 0, 0, 0);
                }
            }
        }

        const int trow = t0 + lg * 4;
#pragma unroll
        for (int n = 0; n < 8; ++n) {
            const int d = d0 + n * 16 + lr;
#pragma unroll
            for (int r = 0; r < 4; ++r)
                partials[((size_t)z * NN + trow + r) * HID + d] = acc[n][r];
        }
    } else {
        // --- w2p column pass ---
        __shared__ float red[4][64];
        const int r = blockIdx.x - 384;
        const int wq = r % 48;           // u64 word index (64 s-columns)
        const int tc = r / 48;           // 256-t chunk
        const int wv = threadIdx.x >> 6, l = threadIdx.x & 63;
        const unsigned long long* mt = (const unsigned long long*)maskT32;
        float acc = 0.0f;
#pragma unroll 4
        for (int it = 0; it < 64; ++it) {
            const int t = tc * 256 + wv * 64 + it;
            unsigned long long word = mt[(long long)t * 48 + wq];  // wave-uniform
            acc += ((word >> l) & 1ULL) ? dinv[t] : 0.0f;
        }
        red[wv][l] = acc;
        __syncthreads();
        if (threadIdx.x < 64)
            w2p[tc * NN + wq * 64 + threadIdx.x] =
                red[0][threadIdx.x] + red[1][threadIdx.x] + red[2][threadIdx.x] + red[3][threadIdx.x];
    }
}

// ---------------------------------------------------------------------------
// L4: vredhead — vred (k-slice reduce, dinv/bias/relu, weighted col-sum) then
// the LAST block (device-scope counter) runs the head MLP inline.
// grid 384 x 256.
// ---------------------------------------------------------------------------
__global__ __launch_bounds__(256) void k_vredhead(const float* __restrict__ partials,
                                                  const float* __restrict__ dinv,
                                                  const float* __restrict__ b1,
                                                  const float* __restrict__ w2p,
                                                  float* __restrict__ vp,
                                                  unsigned int* __restrict__ cnt,
                                                  const float* __restrict__ W2,
                                                  const float* __restrict__ b2,
                                                  const float* __restrict__ l1W,
                                                  const float* __restrict__ l1b,
                                                  const float* __restrict__ lng,
                                                  const float* __restrict__ lnb,
                                                  const float* __restrict__ l2W,
                                                  const float* __restrict__ l2b,
                                                  float* __restrict__ out) {
    __shared__ float w2s[8];
    __shared__ int islast;
    const int b = blockIdx.x, d = threadIdx.x;
    if (threadIdx.x < 8) {
        const int t = b * 8 + threadIdx.x;
        float a = 0.0f;
#pragma unroll
        for (int tc = 0; tc < 12; ++tc) a += w2p[tc * NN + t];
        w2s[threadIdx.x] = dinv[t] * a;
    }
    __syncthreads();
    const float bb = b1[d];
    float vacc = 0.0f;
#pragma unroll
    for (int i = 0; i < 8; ++i) {
        const int t = b * 8 + i;
        float ssum = partials[((size_t)0 * NN + t) * HID + d]
                   + partials[((size_t)1 * NN + t) * HID + d]
                   + partials[((size_t)2 * NN + t) * HID + d]
                   + partials[((size_t)3 * NN + t) * HID + d];
        float h = fmaxf(fmaf(dinv[t], ssum, bb), 0.0f);
        vacc = fmaf(w2s[i], h, vacc);
    }
    vp[b * HID + d] = vacc;
    __threadfence();                       // release vp at device scope
    if (threadIdx.x == 0)
        islast = (atomicAdd(cnt, 1u) == 383u) ? 1 : 0;
    __syncthreads();
    if (!islast) return;
    __threadfence();                       // acquire

    // ---- head (last block only) ----
    __shared__ float vs[HID], gs[HID], zs[HID], red[4];
    float v = 0.0f;
    for (int c = 0; c < 384; ++c) v += vp[c * HID + d];
    vs[d] = v;
    __syncthreads();
    float a = 0.0f;
    for (int k = 0; k < HID; ++k) a = fmaf(vs[k], W2[k * HID + d], a);
    gs[d] = b2[d] + a * (1.0f / 3072.0f);
    __syncthreads();
    float z1 = l1b[d];
    for (int k = 0; k < HID; ++k) z1 = fmaf(gs[k], l1W[k * HID + d], z1);
    z1 = fmaxf(z1, 0.0f);
    float sum = z1;
    for (int o = 1; o < 64; o <<= 1) sum += __shfl_xor(sum, o);
    if ((d & 63) == 0) red[d >> 6] = sum;
    __syncthreads();
    float mu = (red[0] + red[1] + red[2] + red[3]) * (1.0f / 256.0f);
    __syncthreads();
    float diff = z1 - mu, sq = diff * diff;
    for (int o = 1; o < 64; o <<= 1) sq += __shfl_xor(sq, o);
    if ((d & 63) == 0) red[d >> 6] = sq;
    __syncthreads();
    float var = (red[0] + red[1] + red[2] + red[3]) * (1.0f / 256.0f);
    float zn = diff * rsqrtf(var + 1e-5f) * lng[d] + lnb[d];
    zs[d] = zn;
    __syncthreads();
    if (d < 32) {
        float o = l2b[d];
        for (int k = 0; k < HID; ++k) o = fmaf(zs[k], l2W[k * 32 + d], o);
        out[d] = o;
    }
}

// ---------------------------------------------------------------------------
extern "C" void kernel_launch(void* const* d_in, const int* in_sizes, int n_in,
                              void* d_out, int out_size, void* d_ws, size_t ws_size,
                              hipStream_t stream) {
    const float* x     = (const float*)d_in[0];
    const float* attn  = (const float*)d_in[1];
    const float* agg_w = (const float*)d_in[4];
    const float* agg_b = (const float*)d_in[5];
    const float* W1    = (const float*)d_in[6];
    const float* b1    = (const float*)d_in[7];
    const float* W2    = (const float*)d_in[8];
    const float* b2    = (const float*)d_in[9];
    const float* l1W   = (const float*)d_in[10];
    const float* l1b   = (const float*)d_in[11];
    const float* lng   = (const float*)d_in[12];
    const float* lnb   = (const float*)d_in[13];
    const float* l2W   = (const float*)d_in[14];
    const float* l2b   = (const float*)d_in[15];
    float* out = (float*)d_out;

    char* ws = (char*)d_ws;
    size_t off = 0;
    auto alloc = [&](size_t bytes) -> void* {
        off = (off + 255) & ~(size_t)255;
        void* p = ws + off;
        off += bytes;
        return p;
    };
    unsigned int*   maskT32 = (unsigned int*)alloc((size_t)NN * NW32 * 4);
    float*          dinv  = (float*)alloc((size_t)NN * 4);
    unsigned short* dinvb = (unsigned short*)alloc((size_t)NN * 2);
    float*          w2p   = (float*)alloc((size_t)12 * NN * 4);
    unsigned short* y1t   = (unsigned short*)alloc((size_t)HID * NN * 2);
    float*          part  = (float*)alloc((size_t)4 * NN * HID * 4);
    float*          vp    = (float*)alloc((size_t)384 * HID * 4);
    unsigned int*   cnt   = (unsigned int*)alloc(4);

    hipLaunchKernelGGL(k_adj_y1,   dim3(1536), dim3(256), 0, stream,
                       attn, agg_w, agg_b, x, W1, maskT32, y1t);
    hipLaunchKernelGGL(k_dinv,     dim3(12),   dim3(256), 0, stream, maskT32, dinv, dinvb, cnt);
    hipLaunchKernelGGL(k_prop,     dim3(960),  dim3(256), 0, stream,
                       maskT32, dinvb, y1t, dinv, part, w2p);
    hipLaunchKernelGGL(k_vredhead, dim3(384),  dim3(256), 0, stream,
                       part, dinv, b1, w2p, vp, cnt,
                       W2, b2, l1W, l1b, lng, lnb, l2W, l2b, out);
}

// Round 5
// 193.341 us; speedup vs baseline: 1.0080x; 1.0080x over previous
//
#include <hip/hip_runtime.h>
#include <hip/hip_bf16.h>

// Problem constants
#define NN     3072
#define NW32   96          // 3072/32 u32-words per maskT row
#define NB8    384         // 3072/8 bytes per maskT row
#define INCH   128
#define HID    256
#define NHEADS 12
#define PLANE  9437184LL   // 3072*3072

typedef __attribute__((ext_vector_type(8))) short     s16x8;
typedef __attribute__((ext_vector_type(4))) float     f32x4;
typedef __attribute__((ext_vector_type(8))) unsigned short u16x8;
typedef __attribute__((ext_vector_type(4))) unsigned int   u32x4;

__device__ inline unsigned short bf16_rne(float f) {
    unsigned int u = __float_as_uint(f);
    u += 0x7FFFu + ((u >> 16) & 1u);
    return (unsigned short)(u >> 16);
}

// ---------------------------------------------------------------------------
// L1: role-split launch.
//  blocks [0,1152): adj — stream attn (453 MB). Tile 1024t x 8s: each wave owns
//      2 s-rows and reads 4 KB sequential per (row, plane) visit (4x f32x4
//      wave-loads back-to-back) -> long DRAM runs. Bits packed to byte-granular
//      maskT8 (same image as u32/u64 mask words; block owns its s-byte column).
//  blocks [1152,1536): y1 — y1t[d][s] = bf16((x@W1)[s][d]) transposed store.
// ---------------------------------------------------------------------------
__global__ __launch_bounds__(256) void k_adj_y1(const float* __restrict__ attn,
                                                const float* __restrict__ agg_w,
                                                const float* __restrict__ agg_b,
                                                const float* __restrict__ x,
                                                const float* __restrict__ W1,
                                                unsigned char* __restrict__ maskT8,
                                                unsigned short* __restrict__ y1t) {
    __shared__ unsigned char lb[4][1024];    // adj: per-wave 2-bit contribs
    __shared__ float xs[8][INCH];            // y1

    if (blockIdx.x < 1152) {
        const int w = threadIdx.x >> 6, l = threadIdx.x & 63;
        const int t0 = (blockIdx.x % 3) * 1024;
        const int s0 = (blockIdx.x / 3) * 8;
        const int r0 = s0 + 2 * w;
        const float thr = -agg_b[0];

        f32x4 acc[2][4];
#pragma unroll
        for (int r = 0; r < 2; ++r)
#pragma unroll
            for (int q = 0; q < 4; ++q) acc[r][q] = (f32x4){0.f, 0.f, 0.f, 0.f};

        const float* base0 = attn + (long long)r0 * NN + t0 + 4 * l;
#pragma unroll 1
        for (int c = 0; c < NHEADS; ++c) {
            const float wcv = agg_w[c];
            const float* pc = base0 + (long long)c * PLANE;
#pragma unroll
            for (int r = 0; r < 2; ++r) {
#pragma unroll
                for (int q = 0; q < 4; ++q) {
                    f32x4 v = *(const f32x4*)(pc + r * NN + q * 256);
                    acc[r][q][0] = fmaf(wcv, v[0], acc[r][q][0]);
                    acc[r][q][1] = fmaf(wcv, v[1], acc[r][q][1]);
                    acc[r][q][2] = fmaf(wcv, v[2], acc[r][q][2]);
                    acc[r][q][3] = fmaf(wcv, v[3], acc[r][q][3]);
                }
            }
        }

        // pack 2 rows x 16 t per lane -> LDS bytes (bits 0,1 of each byte)
#pragma unroll
        for (int q = 0; q < 4; ++q) {
#pragma unroll
            for (int j = 0; j < 4; ++j) {
                const int tt = q * 256 + 4 * l + j;
                const int t  = t0 + tt;
                unsigned b0 = (acc[0][q][j] > thr || r0 == t)     ? 1u : 0u;
                unsigned b1 = (acc[1][q][j] > thr || r0 + 1 == t) ? 1u : 0u;
                lb[w][tt] = (unsigned char)(b0 | (b1 << 1));
            }
        }
        __syncthreads();
        const int sb = s0 >> 3;
        for (int k = threadIdx.x; k < 1024; k += 256) {
            unsigned v = (unsigned)lb[0][k] | ((unsigned)lb[1][k] << 2)
                       | ((unsigned)lb[2][k] << 4) | ((unsigned)lb[3][k] << 6);
            maskT8[(long long)(t0 + k) * NB8 + sb] = (unsigned char)v;
        }
    } else {
        // --- y1: block = 8 s-rows, thread = d ---
        int s0 = (blockIdx.x - 1152) * 8;
        for (int i = threadIdx.x; i < 8 * INCH; i += 256)
            xs[i >> 7][i & 127] = x[s0 * INCH + i];
        __syncthreads();
        int d = threadIdx.x;
        float acc[8] = {0, 0, 0, 0, 0, 0, 0, 0};
        for (int k = 0; k < INCH; ++k) {
            float w = W1[k * HID + d];
#pragma unroll
            for (int r = 0; r < 8; ++r) acc[r] = fmaf(xs[r][k], w, acc[r]);
        }
        u16x8 v;
#pragma unroll
        for (int r = 0; r < 8; ++r) v[r] = bf16_rne(acc[r]);
        *(u16x8*)(y1t + (long long)d * NN + s0) = v;
    }
}

// ---------------------------------------------------------------------------
// L2: deg[t] = popcount(maskT row t); dinv = rsqrt(deg); dinvb = bf16(dinv).
// grid 12 x 256.
// ---------------------------------------------------------------------------
__global__ __launch_bounds__(256) void k_dinv(const unsigned int* __restrict__ maskT32,
                                              float* __restrict__ dinv,
                                              unsigned short* __restrict__ dinvb) {
    int t = blockIdx.x * 256 + threadIdx.x;
    const u32x4* row = (const u32x4*)(maskT32 + (long long)t * NW32);
    int deg = 0;
#pragma unroll
    for (int i = 0; i < 24; ++i) {
        u32x4 v = row[i];
        deg += __popc(v[0]) + __popc(v[1]) + __popc(v[2]) + __popc(v[3]);
    }
    float di = rsqrtf((float)deg);   // deg >= 1 (self loop)
    dinv[t] = di;
    dinvb[t] = bf16_rne(di);
}

// ---------------------------------------------------------------------------
// L3: role-split launch.
//  blocks [0,384):   prop1 MFMA GEMM, in-register A expansion from maskT bits.
//  blocks [384,960): w2p column pass.
// ---------------------------------------------------------------------------
__global__ __launch_bounds__(256) void k_prop(const unsigned int* __restrict__ maskT32,
                                              const unsigned short* __restrict__ dinvb,
                                              const unsigned short* __restrict__ y1t,
                                              const float* __restrict__ dinv,
                                              float* __restrict__ partials,
                                              float* __restrict__ w2p) {
    if (blockIdx.x < 384) {
        const int w = threadIdx.x >> 6, l = threadIdx.x & 63;
        const int lr = l & 15, lg = l >> 4;
        const int t0 = (blockIdx.x % 48) * 64 + w * 16;
        const int d0 = ((blockIdx.x / 48) % 2) * 128;
        const int z  = blockIdx.x / 96;

        const unsigned long long* mrow =
            (const unsigned long long*)(maskT32 + (long long)(t0 + lr) * NW32) + z * 12;

        const unsigned short* B[8];
#pragma unroll
        for (int n = 0; n < 8; ++n)
            B[n] = y1t + (long long)(d0 + n * 16 + lr) * NN;

        f32x4 acc[8];
#pragma unroll
        for (int n = 0; n < 8; ++n) acc[n] = (f32x4){0.f, 0.f, 0.f, 0.f};

#pragma unroll 2
        for (int kw = 0; kw < 12; ++kw) {
            unsigned long long word = mrow[kw];
#pragma unroll
            for (int half = 0; half < 2; ++half) {
                const int k0 = z * 768 + kw * 64 + half * 32 + lg * 8;
                unsigned int bits = (unsigned int)((word >> (half * 32 + lg * 8)) & 0xFFULL);
                u16x8 dv = *(const u16x8*)(dinvb + k0);
                s16x8 av;
#pragma unroll
                for (int j = 0; j < 8; ++j)
                    av[j] = ((bits >> j) & 1u) ? (short)dv[j] : (short)0;
#pragma unroll
                for (int n = 0; n < 8; ++n) {
                    s16x8 bv = *(const s16x8*)(const void*)(B[n] + k0);
                    acc[n] = __builtin_amdgcn_mfma_f32_16x16x32_bf16(av, bv, acc[n], 0, 0, 0);
                }
            }
        }

        const int trow = t0 + lg * 4;
#pragma unroll
        for (int n = 0; n < 8; ++n) {
            const int d = d0 + n * 16 + lr;
#pragma unroll
            for (int r = 0; r < 4; ++r)
                partials[((size_t)z * NN + trow + r) * HID + d] = acc[n][r];
        }
    } else {
        // --- w2p column pass ---
        __shared__ float red[4][64];
        const int r = blockIdx.x - 384;
        const int wq = r % 48;           // u64 word index (64 s-columns)
        const int tc = r / 48;           // 256-t chunk
        const int wv = threadIdx.x >> 6, l = threadIdx.x & 63;
        const unsigned long long* mt = (const unsigned long long*)maskT32;
        float acc = 0.0f;
#pragma unroll 4
        for (int it = 0; it < 64; ++it) {
            const int t = tc * 256 + wv * 64 + it;
            unsigned long long word = mt[(long long)t * 48 + wq];  // wave-uniform
            acc += ((word >> l) & 1ULL) ? dinv[t] : 0.0f;
        }
        red[wv][l] = acc;
        __syncthreads();
        if (threadIdx.x < 64)
            w2p[tc * NN + wq * 64 + threadIdx.x] =
                red[0][threadIdx.x] + red[1][threadIdx.x] + red[2][threadIdx.x] + red[3][threadIdx.x];
    }
}

// ---------------------------------------------------------------------------
// L4: vred — reduce k-slices, apply dinv[t]/bias/relu, fold weighted col-sum.
// Also reduces w2p -> w2sum for its 8 t-rows. grid 384 x 256.
// ---------------------------------------------------------------------------
__global__ __launch_bounds__(256) void k_vred(const float* __restrict__ partials,
                                              const float* __restrict__ dinv,
                                              const float* __restrict__ b1,
                                              const float* __restrict__ w2p,
                                              float* __restrict__ vp) {
    __shared__ float w2s[8];
    const int b = blockIdx.x, d = threadIdx.x;
    if (threadIdx.x < 8) {
        const int t = b * 8 + threadIdx.x;
        float a = 0.0f;
#pragma unroll
        for (int tc = 0; tc < 12; ++tc) a += w2p[tc * NN + t];
        w2s[threadIdx.x] = dinv[t] * a;
    }
    __syncthreads();
    const float bb = b1[d];
    float vacc = 0.0f;
#pragma unroll
    for (int i = 0; i < 8; ++i) {
        const int t = b * 8 + i;
        float ssum = partials[((size_t)0 * NN + t) * HID + d]
                   + partials[((size_t)1 * NN + t) * HID + d]
                   + partials[((size_t)2 * NN + t) * HID + d]
                   + partials[((size_t)3 * NN + t) * HID + d];
        float h = fmaxf(fmaf(dinv[t], ssum, bb), 0.0f);
        vacc = fmaf(w2s[i], h, vacc);
    }
    vp[b * HID + d] = vacc;
}

// ---------------------------------------------------------------------------
// L5: head. g = b2 + (v@W2)/3072 ; z=relu(g@l1W+l1b); LN; out = z@l2W+l2b.
// ---------------------------------------------------------------------------
__global__ __launch_bounds__(256) void k_head(const float* __restrict__ vp,
                                              const float* __restrict__ W2,
                                              const float* __restrict__ b2,
                                              const float* __restrict__ l1W,
                                              const float* __restrict__ l1b,
                                              const float* __restrict__ lng,
                                              const float* __restrict__ lnb,
                                              const float* __restrict__ l2W,
                                              const float* __restrict__ l2b,
                                              float* __restrict__ out) {
    __shared__ float vs[HID], gs[HID], zs[HID], red[4];
    int d = threadIdx.x;
    float v = 0.0f;
    for (int c = 0; c < 384; ++c) v += vp[c * HID + d];
    vs[d] = v;
    __syncthreads();
    float a = 0.0f;
    for (int k = 0; k < HID; ++k) a = fmaf(vs[k], W2[k * HID + d], a);
    gs[d] = b2[d] + a * (1.0f / 3072.0f);
    __syncthreads();
    float z1 = l1b[d];
    for (int k = 0; k < HID; ++k) z1 = fmaf(gs[k], l1W[k * HID + d], z1);
    z1 = fmaxf(z1, 0.0f);
    float sum = z1;
    for (int o = 1; o < 64; o <<= 1) sum += __shfl_xor(sum, o);
    if ((d & 63) == 0) red[d >> 6] = sum;
    __syncthreads();
    float mu = (red[0] + red[1] + red[2] + red[3]) * (1.0f / 256.0f);
    __syncthreads();
    float diff = z1 - mu, sq = diff * diff;
    for (int o = 1; o < 64; o <<= 1) sq += __shfl_xor(sq, o);
    if ((d & 63) == 0) red[d >> 6] = sq;
    __syncthreads();
    float var = (red[0] + red[1] + red[2] + red[3]) * (1.0f / 256.0f);
    float zn = diff * rsqrtf(var + 1e-5f) * lng[d] + lnb[d];
    zs[d] = zn;
    __syncthreads();
    if (d < 32) {
        float o = l2b[d];
        for (int k = 0; k < HID; ++k) o = fmaf(zs[k], l2W[k * 32 + d], o);
        out[d] = o;
    }
}

// ---------------------------------------------------------------------------
extern "C" void kernel_launch(void* const* d_in, const int* in_sizes, int n_in,
                              void* d_out, int out_size, void* d_ws, size_t ws_size,
                              hipStream_t stream) {
    const float* x     = (const float*)d_in[0];
    const float* attn  = (const float*)d_in[1];
    const float* agg_w = (const float*)d_in[4];
    const float* agg_b = (const float*)d_in[5];
    const float* W1    = (const float*)d_in[6];
    const float* b1    = (const float*)d_in[7];
    const float* W2    = (const float*)d_in[8];
    const float* b2    = (const float*)d_in[9];
    const float* l1W   = (const float*)d_in[10];
    const float* l1b   = (const float*)d_in[11];
    const float* lng   = (const float*)d_in[12];
    const float* lnb   = (const float*)d_in[13];
    const float* l2W   = (const float*)d_in[14];
    const float* l2b   = (const float*)d_in[15];
    float* out = (float*)d_out;

    char* ws = (char*)d_ws;
    size_t off = 0;
    auto alloc = [&](size_t bytes) -> void* {
        off = (off + 255) & ~(size_t)255;
        void* p = ws + off;
        off += bytes;
        return p;
    };
    unsigned int*   maskT32 = (unsigned int*)alloc((size_t)NN * NW32 * 4);
    float*          dinv  = (float*)alloc((size_t)NN * 4);
    unsigned short* dinvb = (unsigned short*)alloc((size_t)NN * 2);
    float*          w2p   = (float*)alloc((size_t)12 * NN * 4);
    unsigned short* y1t   = (unsigned short*)alloc((size_t)HID * NN * 2);
    float*          part  = (float*)alloc((size_t)4 * NN * HID * 4);
    float*          vp    = (float*)alloc((size_t)384 * HID * 4);

    hipLaunchKernelGGL(k_adj_y1, dim3(1536), dim3(256), 0, stream,
                       attn, agg_w, agg_b, x, W1, (unsigned char*)maskT32, y1t);
    hipLaunchKernelGGL(k_dinv,   dim3(12),   dim3(256), 0, stream, maskT32, dinv, dinvb);
    hipLaunchKernelGGL(k_prop,   dim3(960),  dim3(256), 0, stream,
                       maskT32, dinvb, y1t, dinv, part, w2p);
    hipLaunchKernelGGL(k_vred,   dim3(384),  dim3(256), 0, stream, part, dinv, b1, w2p, vp);
    hipLaunchKernelGGL(k_head,   dim3(1),    dim3(256), 0, stream,
                       vp, W2, b2, l1W, l1b, lng, lnb, l2W, l2b, out);
}

// Round 6
// 186.565 us; speedup vs baseline: 1.0446x; 1.0363x over previous
//
#include <hip/hip_runtime.h>
#include <hip/hip_bf16.h>

// Problem constants
#define NN     3072
#define NW32   96          // 3072/32 u32-words per mask row
#define INCH   128
#define HID    256
#define NHEADS 12
#define PLANE  9437184LL   // 3072*3072
#define PIECEF 2048        // floats per block-piece per (slab,c)
#define NADJ   768         // adj blocks
#define SLABF  (NADJ*PIECEF)   // 1,572,864 floats = 512 rows = 6.29 MB
#define NSLAB  6               // PLANE / SLABF

typedef __attribute__((ext_vector_type(8))) short     s16x8;
typedef __attribute__((ext_vector_type(4))) float     f32x4;
typedef __attribute__((ext_vector_type(8))) unsigned short u16x8;
typedef __attribute__((ext_vector_type(4))) unsigned int   u32x4;

__device__ inline unsigned short bf16_rne(float f) {
    unsigned int u = __float_as_uint(f);
    u += 0x7FFFu + ((u >> 16) & 1u);
    return (unsigned short)(u >> 16);
}

// ---------------------------------------------------------------------------
// L1: role-split launch.
//  blocks [0,768): adj — slab-synchronized linear sweep of attn (453 MB).
//      For slab i (6.3 MB window): each block owns 2048 consecutive floats;
//      loop c=0..11 reading that window from each plane (coalesced f32x4,
//      lanes contiguous), accumulate in regs; threshold; LDS nibble-pack ->
//      row-major mask bits (coalesced u32 stores). Whole-grid frontier at any
//      instant ~ one slab per plane (narrow, copy-like).
//  blocks [768,1152): y1 — y1t[d][s] = bf16((x@W1)[s][d]) transposed store.
// ---------------------------------------------------------------------------
__global__ __launch_bounds__(256) void k_adj_y1(const float* __restrict__ attn,
                                                const float* __restrict__ agg_w,
                                                const float* __restrict__ agg_b,
                                                const float* __restrict__ x,
                                                const float* __restrict__ W1,
                                                unsigned int* __restrict__ mask32,
                                                unsigned short* __restrict__ y1t) {
    __shared__ unsigned char nib[512];       // adj: one nibble per f32x4 group
    __shared__ float xs[8][INCH];            // y1

    if (blockIdx.x < NADJ) {
        const int b = blockIdx.x;
        const int j = threadIdx.x;
        const float thr = -agg_b[0];
        float wc[NHEADS];
#pragma unroll
        for (int c = 0; c < NHEADS; ++c) wc[c] = agg_w[c];

#pragma unroll 1
        for (int i = 0; i < NSLAB; ++i) {
            const int P = i * SLABF + b * PIECEF;    // float offset in plane

            f32x4 acc[2];
            acc[0] = (f32x4){0.f, 0.f, 0.f, 0.f};
            acc[1] = (f32x4){0.f, 0.f, 0.f, 0.f};
#pragma unroll 1
            for (int c = 0; c < NHEADS; ++c) {
                const float* pc = attn + (long long)c * PLANE + P;
                f32x4 v0 = *(const f32x4*)(pc + 4 * j);            // q=0
                f32x4 v1 = *(const f32x4*)(pc + 4 * (256 + j));    // q=1
                const float w = wc[c];
#pragma unroll
                for (int k = 0; k < 4; ++k) {
                    acc[0][k] = fmaf(w, v0[k], acc[0][k]);
                    acc[1][k] = fmaf(w, v1[k], acc[1][k]);
                }
            }

            // threshold + diagonal -> nibbles
#pragma unroll
            for (int q = 0; q < 2; ++q) {
                const int g = q * 256 + j;             // f32x4 index in piece
                const unsigned off0 = (unsigned)P + 4u * g;
                unsigned bits = 0;
#pragma unroll
                for (int k = 0; k < 4; ++k) {
                    const unsigned off = off0 + k;
                    // diagonal (t==s) <=> off % 3073 == 0
                    bool pred = (acc[q][k] > thr) || (off % 3073u == 0u);
                    bits |= pred ? (1u << k) : 0u;
                }
                nib[g] = (unsigned char)bits;
            }
            __syncthreads();
            if (j < 64) {
                unsigned a = *(const unsigned*)(nib + 8 * j);
                unsigned c2 = *(const unsigned*)(nib + 8 * j + 4);
                a &= 0x0F0F0F0Fu;  a = (a | (a >> 4)) & 0x00FF00FFu;  a = (a | (a >> 8)) & 0x0000FFFFu;
                c2 &= 0x0F0F0F0Fu; c2 = (c2 | (c2 >> 4)) & 0x00FF00FFu; c2 = (c2 | (c2 >> 8)) & 0x0000FFFFu;
                mask32[(P >> 5) + j] = a | (c2 << 16);
            }
            __syncthreads();   // nib reused next slab
        }
    } else {
        // --- y1: block = 8 s-rows, thread = d ---
        int s0 = (blockIdx.x - NADJ) * 8;
        for (int i = threadIdx.x; i < 8 * INCH; i += 256)
            xs[i >> 7][i & 127] = x[s0 * INCH + i];
        __syncthreads();
        int d = threadIdx.x;
        float acc[8] = {0, 0, 0, 0, 0, 0, 0, 0};
        for (int k = 0; k < INCH; ++k) {
            float w = W1[k * HID + d];
#pragma unroll
            for (int r = 0; r < 8; ++r) acc[r] = fmaf(xs[r][k], w, acc[r]);
        }
        u16x8 v;
#pragma unroll
        for (int r = 0; r < 8; ++r) v[r] = bf16_rne(acc[r]);
        *(u16x8*)(y1t + (long long)d * NN + s0) = v;
    }
}

// ---------------------------------------------------------------------------
// L2: pack — bit-transpose row-major mask -> maskT. Wave per 64x64-bit tile
// via 64 ballots. grid 576 x 256 (4 waves/block, 2304 tiles).
// ---------------------------------------------------------------------------
__global__ __launch_bounds__(256) void k_pack(const unsigned int* __restrict__ mask32,
                                              unsigned long long* __restrict__ maskT64) {
    const int w = threadIdx.x >> 6, l = threadIdx.x & 63;
    const int tile = blockIdx.x * 4 + w;
    const int sq = tile % 48, tq = tile / 48;
    const unsigned long long* m64 = (const unsigned long long*)mask32;
    unsigned long long myw = m64[(long long)(sq * 64 + l) * 48 + tq];
#pragma unroll 8
    for (int tt = 0; tt < 64; ++tt) {
        unsigned long long bal = __ballot((myw >> tt) & 1ULL);
        if (l == tt)
            maskT64[(long long)(tq * 64 + tt) * 48 + sq] = bal;
    }
}

// ---------------------------------------------------------------------------
// L3: deg[t] = popcount(maskT row t); dinv = rsqrt(deg); dinvb = bf16(dinv).
// grid 12 x 256.
// ---------------------------------------------------------------------------
__global__ __launch_bounds__(256) void k_dinv(const unsigned int* __restrict__ maskT32,
                                              float* __restrict__ dinv,
                                              unsigned short* __restrict__ dinvb) {
    int t = blockIdx.x * 256 + threadIdx.x;
    const u32x4* row = (const u32x4*)(maskT32 + (long long)t * NW32);
    int deg = 0;
#pragma unroll
    for (int i = 0; i < 24; ++i) {
        u32x4 v = row[i];
        deg += __popc(v[0]) + __popc(v[1]) + __popc(v[2]) + __popc(v[3]);
    }
    float di = rsqrtf((float)deg);   // deg >= 1 (self loop)
    dinv[t] = di;
    dinvb[t] = bf16_rne(di);
}

// ---------------------------------------------------------------------------
// L4: role-split launch.
//  blocks [0,384):   prop1 MFMA GEMM, in-register A expansion from maskT bits.
//  blocks [384,960): w2p column pass.
// ---------------------------------------------------------------------------
__global__ __launch_bounds__(256) void k_prop(const unsigned int* __restrict__ maskT32,
                                              const unsigned short* __restrict__ dinvb,
                                              const unsigned short* __restrict__ y1t,
                                              const float* __restrict__ dinv,
                                              float* __restrict__ partials,
                                              float* __restrict__ w2p) {
    if (blockIdx.x < 384) {
        const int w = threadIdx.x >> 6, l = threadIdx.x & 63;
        const int lr = l & 15, lg = l >> 4;
        const int t0 = (blockIdx.x % 48) * 64 + w * 16;
        const int d0 = ((blockIdx.x / 48) % 2) * 128;
        const int z  = blockIdx.x / 96;

        const unsigned long long* mrow =
            (const unsigned long long*)(maskT32 + (long long)(t0 + lr) * NW32) + z * 12;

        const unsigned short* B[8];
#pragma unroll
        for (int n = 0; n < 8; ++n)
            B[n] = y1t + (long long)(d0 + n * 16 + lr) * NN;

        f32x4 acc[8];
#pragma unroll
        for (int n = 0; n < 8; ++n) acc[n] = (f32x4){0.f, 0.f, 0.f, 0.f};

#pragma unroll 2
        for (int kw = 0; kw < 12; ++kw) {
            unsigned long long word = mrow[kw];
#pragma unroll
            for (int half = 0; half < 2; ++half) {
                const int k0 = z * 768 + kw * 64 + half * 32 + lg * 8;
                unsigned int bits = (unsigned int)((word >> (half * 32 + lg * 8)) & 0xFFULL);
                u16x8 dv = *(const u16x8*)(dinvb + k0);
                s16x8 av;
#pragma unroll
                for (int j = 0; j < 8; ++j)
                    av[j] = ((bits >> j) & 1u) ? (short)dv[j] : (short)0;
#pragma unroll
                for (int n = 0; n < 8; ++n) {
                    s16x8 bv = *(const s16x8*)(const void*)(B[n] + k0);
                    acc[n] = __builtin_amdgcn_mfma_f32_16x16x32_bf16(av, bv, acc[n], 0, 0, 0);
                }
            }
        }

        const int trow = t0 + lg * 4;
#pragma unroll
        for (int n = 0; n < 8; ++n) {
            const int d = d0 + n * 16 + lr;
#pragma unroll
            for (int r = 0; r < 4; ++r)
                partials[((size_t)z * NN + trow + r) * HID + d] = acc[n][r];
        }
    } else {
        // --- w2p column pass ---
        __shared__ float red[4][64];
        const int r = blockIdx.x - 384;
        const int wq = r % 48;           // u64 word index (64 s-columns)
        const int tc = r / 48;           // 256-t chunk
        const int wv = threadIdx.x >> 6, l = threadIdx.x & 63;
        const unsigned long long* mt = (const unsigned long long*)maskT32;
        float acc = 0.0f;
#pragma unroll 4
        for (int it = 0; it < 64; ++it) {
            const int t = tc * 256 + wv * 64 + it;
            unsigned long long word = mt[(long long)t * 48 + wq];  // wave-uniform
            acc += ((word >> l) & 1ULL) ? dinv[t] : 0.0f;
        }
        red[wv][l] = acc;
        __syncthreads();
        if (threadIdx.x < 64)
            w2p[tc * NN + wq * 64 + threadIdx.x] =
                red[0][threadIdx.x] + red[1][threadIdx.x] + red[2][threadIdx.x] + red[3][threadIdx.x];
    }
}

// ---------------------------------------------------------------------------
// L5: vred — reduce k-slices, apply dinv[t]/bias/relu, fold weighted col-sum.
// grid 384 x 256.
// ---------------------------------------------------------------------------
__global__ __launch_bounds__(256) void k_vred(const float* __restrict__ partials,
                                              const float* __restrict__ dinv,
                                              const float* __restrict__ b1,
                                              const float* __restrict__ w2p,
                                              float* __restrict__ vp) {
    __shared__ float w2s[8];
    const int b = blockIdx.x, d = threadIdx.x;
    if (threadIdx.x < 8) {
        const int t = b * 8 + threadIdx.x;
        float a = 0.0f;
#pragma unroll
        for (int tc = 0; tc < 12; ++tc) a += w2p[tc * NN + t];
        w2s[threadIdx.x] = dinv[t] * a;
    }
    __syncthreads();
    const float bb = b1[d];
    float vacc = 0.0f;
#pragma unroll
    for (int i = 0; i < 8; ++i) {
        const int t = b * 8 + i;
        float ssum = partials[((size_t)0 * NN + t) * HID + d]
                   + partials[((size_t)1 * NN + t) * HID + d]
                   + partials[((size_t)2 * NN + t) * HID + d]
                   + partials[((size_t)3 * NN + t) * HID + d];
        float h = fmaxf(fmaf(dinv[t], ssum, bb), 0.0f);
        vacc = fmaf(w2s[i], h, vacc);
    }
    vp[b * HID + d] = vacc;
}

// ---------------------------------------------------------------------------
// L6: head. g = b2 + (v@W2)/3072 ; z=relu(g@l1W+l1b); LN; out = z@l2W+l2b.
// ---------------------------------------------------------------------------
__global__ __launch_bounds__(256) void k_head(const float* __restrict__ vp,
                                              const float* __restrict__ W2,
                                              const float* __restrict__ b2,
                                              const float* __restrict__ l1W,
                                              const float* __restrict__ l1b,
                                              const float* __restrict__ lng,
                                              const float* __restrict__ lnb,
                                              const float* __restrict__ l2W,
                                              const float* __restrict__ l2b,
                                              float* __restrict__ out) {
    __shared__ float vs[HID], gs[HID], zs[HID], red[4];
    int d = threadIdx.x;
    float v = 0.0f;
    for (int c = 0; c < 384; ++c) v += vp[c * HID + d];
    vs[d] = v;
    __syncthreads();
    float a = 0.0f;
    for (int k = 0; k < HID; ++k) a = fmaf(vs[k], W2[k * HID + d], a);
    gs[d] = b2[d] + a * (1.0f / 3072.0f);
    __syncthreads();
    float z1 = l1b[d];
    for (int k = 0; k < HID; ++k) z1 = fmaf(gs[k], l1W[k * HID + d], z1);
    z1 = fmaxf(z1, 0.0f);
    float sum = z1;
    for (int o = 1; o < 64; o <<= 1) sum += __shfl_xor(sum, o);
    if ((d & 63) == 0) red[d >> 6] = sum;
    __syncthreads();
    float mu = (red[0] + red[1] + red[2] + red[3]) * (1.0f / 256.0f);
    __syncthreads();
    float diff = z1 - mu, sq = diff * diff;
    for (int o = 1; o < 64; o <<= 1) sq += __shfl_xor(sq, o);
    if ((d & 63) == 0) red[d >> 6] = sq;
    __syncthreads();
    float var = (red[0] + red[1] + red[2] + red[3]) * (1.0f / 256.0f);
    float zn = diff * rsqrtf(var + 1e-5f) * lng[d] + lnb[d];
    zs[d] = zn;
    __syncthreads();
    if (d < 32) {
        float o = l2b[d];
        for (int k = 0; k < HID; ++k) o = fmaf(zs[k], l2W[k * 32 + d], o);
        out[d] = o;
    }
}

// ---------------------------------------------------------------------------
extern "C" void kernel_launch(void* const* d_in, const int* in_sizes, int n_in,
                              void* d_out, int out_size, void* d_ws, size_t ws_size,
                              hipStream_t stream) {
    const float* x     = (const float*)d_in[0];
    const float* attn  = (const float*)d_in[1];
    const float* agg_w = (const float*)d_in[4];
    const float* agg_b = (const float*)d_in[5];
    const float* W1    = (const float*)d_in[6];
    const float* b1    = (const float*)d_in[7];
    const float* W2    = (const float*)d_in[8];
    const float* b2    = (const float*)d_in[9];
    const float* l1W   = (const float*)d_in[10];
    const float* l1b   = (const float*)d_in[11];
    const float* lng   = (const float*)d_in[12];
    const float* lnb   = (const float*)d_in[13];
    const float* l2W   = (const float*)d_in[14];
    const float* l2b   = (const float*)d_in[15];
    float* out = (float*)d_out;

    char* ws = (char*)d_ws;
    size_t off = 0;
    auto alloc = [&](size_t bytes) -> void* {
        off = (off + 255) & ~(size_t)255;
        void* p = ws + off;
        off += bytes;
        return p;
    };
    unsigned int*   mask32  = (unsigned int*)alloc((size_t)NN * NW32 * 4);
    unsigned int*   maskT32 = (unsigned int*)alloc((size_t)NN * NW32 * 4);
    float*          dinv  = (float*)alloc((size_t)NN * 4);
    unsigned short* dinvb = (unsigned short*)alloc((size_t)NN * 2);
    float*          w2p   = (float*)alloc((size_t)12 * NN * 4);
    unsigned short* y1t   = (unsigned short*)alloc((size_t)HID * NN * 2);
    float*          part  = (float*)alloc((size_t)4 * NN * HID * 4);
    float*          vp    = (float*)alloc((size_t)384 * HID * 4);

    hipLaunchKernelGGL(k_adj_y1, dim3(1152), dim3(256), 0, stream,
                       attn, agg_w, agg_b, x, W1, mask32, y1t);
    hipLaunchKernelGGL(k_pack,   dim3(576),  dim3(256), 0, stream,
                       mask32, (unsigned long long*)maskT32);
    hipLaunchKernelGGL(k_dinv,   dim3(12),   dim3(256), 0, stream, maskT32, dinv, dinvb);
    hipLaunchKernelGGL(k_prop,   dim3(960),  dim3(256), 0, stream,
                       maskT32, dinvb, y1t, dinv, part, w2p);
    hipLaunchKernelGGL(k_vred,   dim3(384),  dim3(256), 0, stream, part, dinv, b1, w2p, vp);
    hipLaunchKernelGGL(k_head,   dim3(1),    dim3(256), 0, stream,
                       vp, W2, b2, l1W, l1b, lng, lnb, l2W, l2b, out);
}